// Round 9
// baseline (83.217 us; speedup 1.0000x reference)
//
#include <hip/hip_runtime.h>

// N-body all-pairs gravitational force, N=8192, fp32.
//
// Round-9: STAGE-MAJOR inner loop. r3-r8 all plateau at kernel ~30us while
// measured VALU-issue time is ~15us (r5 counters) => ~2x stall invariant to
// TLP/ILP config. Diagnosis: VGPR_Count=36 -> compiler register-minimizes,
// serializing the IBLK "independent" chains; the ~60cyc dep chain
// (3 fma -> rsq -> 2 mul) then dominates. Fix: stage-major source order
// (all subs, then all d2, then all rsq, ...) across GRP=4 pk-groups
// (IBLK=8 bodies/thread), + register prefetch of sh[k+1] to hide ds_read.
//  - BLOCK=128, grid (8,128)=1024 blocks = 2 waves/SIMD; JPER=64, 1KB LDS
//  - partial stores [128][N*3] + reduce pass (no atomics: r5 lesson)
// Issue floor ~8.5us; expecting 12-15us realized.

typedef float v2f __attribute__((ext_vector_type(2)));

constexpr int   NBODY   = 8192;
constexpr int   BLOCK   = 128;
constexpr int   IBLK    = 8;                   // bodies/thread
constexpr int   GRP     = IBLK / 2;            // 4 packed groups
constexpr int   IBODIES = BLOCK * IBLK;        // 1024 i's per block
constexpr int   JSPLIT  = 128;
constexpr int   JPER    = NBODY / JSPLIT;      // 64 j's per block
constexpr float SOFT2   = 0.01f * 0.01f;
constexpr int   OUTE    = NBODY * 3;           // 24576

__global__ __launch_bounds__(BLOCK, 2) void nbody_forces(
    const float* __restrict__ pos,       // [N,3]
    const float* __restrict__ mass,      // [N]
    float*       __restrict__ part)      // [JSPLIT][N*3] partials
{
    const int tid   = threadIdx.x;
    const int iBase = blockIdx.x * IBODIES + tid;
    const int j0    = blockIdx.y * JPER;

    __shared__ float4 sh[JPER + 1];      // +1: prefetch overread pad
    if (tid < JPER) {
        const int j = j0 + tid;
        sh[tid] = make_float4(pos[3 * j + 0], pos[3 * j + 1], pos[3 * j + 2], mass[j]);
    }

    v2f px[GRP], py[GRP], pz[GRP];
    #pragma unroll
    for (int g = 0; g < GRP; ++g) {
        const int i0 = iBase + (2 * g + 0) * BLOCK;
        const int i1 = iBase + (2 * g + 1) * BLOCK;
        px[g] = (v2f){pos[3 * i0 + 0], pos[3 * i1 + 0]};
        py[g] = (v2f){pos[3 * i0 + 1], pos[3 * i1 + 1]};
        pz[g] = (v2f){pos[3 * i0 + 2], pos[3 * i1 + 2]};
    }
    __syncthreads();

    v2f fx[GRP], fy[GRP], fz[GRP];
    #pragma unroll
    for (int g = 0; g < GRP; ++g) {
        fx[g] = (v2f){0.f, 0.f}; fy[g] = (v2f){0.f, 0.f}; fz[g] = (v2f){0.f, 0.f};
    }

    const v2f soft2 = (v2f){SOFT2, SOFT2};

    float4 pj = sh[0];
    #pragma unroll 2
    for (int k = 0; k < JPER; ++k) {
        const float4 pn = sh[k + 1];     // prefetch next j off the critical path
        const v2f jx = (v2f){pj.x, pj.x};
        const v2f jy = (v2f){pj.y, pj.y};
        const v2f jz = (v2f){pj.z, pj.z};
        const v2f jm = (v2f){pj.w, pj.w};

        // ---- stage 1: all displacement vectors (12 pk subs) ----
        v2f dx[GRP], dy[GRP], dz[GRP];
        #pragma unroll
        for (int g = 0; g < GRP; ++g) { dx[g] = jx - px[g]; }
        #pragma unroll
        for (int g = 0; g < GRP; ++g) { dy[g] = jy - py[g]; }
        #pragma unroll
        for (int g = 0; g < GRP; ++g) { dz[g] = jz - pz[g]; }

        // ---- stage 2: all squared distances (interleaved fma chains) ----
        v2f d2[GRP];
        #pragma unroll
        for (int g = 0; g < GRP; ++g) { d2[g] = __builtin_elementwise_fma(dz[g], dz[g], soft2); }
        #pragma unroll
        for (int g = 0; g < GRP; ++g) { d2[g] = __builtin_elementwise_fma(dy[g], dy[g], d2[g]); }
        #pragma unroll
        for (int g = 0; g < GRP; ++g) { d2[g] = __builtin_elementwise_fma(dx[g], dx[g], d2[g]); }

        // ---- stage 3: all rsq (8 v_rsq_f32, back-to-back) ----
        v2f inv[GRP];
        #pragma unroll
        for (int g = 0; g < GRP; ++g) {
            inv[g].x = __builtin_amdgcn_rsqf(d2[g].x);
            inv[g].y = __builtin_amdgcn_rsqf(d2[g].y);
        }

        // ---- stage 4: all force magnitudes (interleaved muls) ----
        v2f s[GRP];
        #pragma unroll
        for (int g = 0; g < GRP; ++g) { s[g] = inv[g] * inv[g]; }
        #pragma unroll
        for (int g = 0; g < GRP; ++g) { s[g] = s[g] * inv[g]; }
        #pragma unroll
        for (int g = 0; g < GRP; ++g) { s[g] = s[g] * jm; }

        // ---- stage 5: all accumulates (12 pk fmas) ----
        #pragma unroll
        for (int g = 0; g < GRP; ++g) { fx[g] = __builtin_elementwise_fma(s[g], dx[g], fx[g]); }
        #pragma unroll
        for (int g = 0; g < GRP; ++g) { fy[g] = __builtin_elementwise_fma(s[g], dy[g], fy[g]); }
        #pragma unroll
        for (int g = 0; g < GRP; ++g) { fz[g] = __builtin_elementwise_fma(s[g], dz[g], fz[g]); }
        // j == i: diff = 0 -> contribution 0, matches reference.

        pj = pn;
    }

    float* dst = part + (size_t)blockIdx.y * OUTE;
    #pragma unroll
    for (int g = 0; g < GRP; ++g) {
        #pragma unroll
        for (int h = 0; h < 2; ++h) {
            const int i = iBase + (2 * g + h) * BLOCK;
            dst[3 * i + 0] = fx[g][h];
            dst[3 * i + 1] = fy[g][h];
            dst[3 * i + 2] = fz[g][h];
        }
    }
}

__global__ __launch_bounds__(256) void reduce_kernel(
    const float* __restrict__ part,      // [JSPLIT][OUTE]
    float*       __restrict__ out)       // [OUTE]
{
    const int e = blockIdx.x * blockDim.x + threadIdx.x;   // 0..OUTE-1
    float s = 0.f;
    #pragma unroll 8
    for (int k = 0; k < JSPLIT; ++k)
        s += part[(size_t)k * OUTE + e];
    out[e] = s;
}

extern "C" void kernel_launch(void* const* d_in, const int* in_sizes, int n_in,
                              void* d_out, int out_size, void* d_ws, size_t ws_size,
                              hipStream_t stream) {
    const float* pos  = (const float*)d_in[0];
    const float* mass = (const float*)d_in[1];
    float* out = (float*)d_out;

    float* part = (float*)d_ws;          // [JSPLIT][OUTE] = 12.6 MB

    dim3 grid(NBODY / IBODIES, JSPLIT);  // (8, 128) = 1024 blocks
    nbody_forces<<<grid, BLOCK, 0, stream>>>(pos, mass, part);

    reduce_kernel<<<OUTE / 256, 256, 0, stream>>>(part, out);
}